// Round 1
// baseline (6723.640 us; speedup 1.0000x reference)
//
#include <hip/hip_runtime.h>
#include <math.h>

#define HID 4096
#define NH 32
#define HD 128
#define SEQ 2048
#define NKT 64
#define HHSZ 256
#define RECENT 512
#define CACHE 768
#define SELN 1536
#define RSQRT_D 0.08838834764831845f

// ---------------- NT GEMM: C[M,N] = A[M,K] * B[N,K]^T, M=2048, N=K=4096 ----
// MODE 0: C row-major [s][o].  MODE 1: scatter to [head][s][d] (o = h*128+d).
template<int MODE>
__global__ __launch_bounds__(256) void gemm_nt(const float* __restrict__ A,
                                               const float* __restrict__ B,
                                               float* __restrict__ C) {
  __shared__ float As[16][132];
  __shared__ float Bs[16][132];
  const int tid = threadIdx.x;
  const int tx = tid & 15, ty = tid >> 4;
  const int m0 = blockIdx.y * 128, n0 = blockIdx.x * 128;
  float acc[8][8] = {};
  for (int k0 = 0; k0 < HID; k0 += 16) {
#pragma unroll
    for (int l = 0; l < 2; ++l) {
      int i = tid + l * 256;          // float4 index 0..511 over 128x16 tile
      int row = i >> 2;
      int col = (i & 3) * 4;
      float4 av = *(const float4*)&A[(size_t)(m0 + row) * HID + k0 + col];
      As[col + 0][row] = av.x; As[col + 1][row] = av.y;
      As[col + 2][row] = av.z; As[col + 3][row] = av.w;
      float4 bv = *(const float4*)&B[(size_t)(n0 + row) * HID + k0 + col];
      Bs[col + 0][row] = bv.x; Bs[col + 1][row] = bv.y;
      Bs[col + 2][row] = bv.z; Bs[col + 3][row] = bv.w;
    }
    __syncthreads();
#pragma unroll
    for (int kk = 0; kk < 16; ++kk) {
      float a[8], b[8];
      *(float4*)&a[0] = *(const float4*)&As[kk][ty * 4];
      *(float4*)&a[4] = *(const float4*)&As[kk][64 + ty * 4];
      *(float4*)&b[0] = *(const float4*)&Bs[kk][tx * 4];
      *(float4*)&b[4] = *(const float4*)&Bs[kk][64 + tx * 4];
#pragma unroll
      for (int i2 = 0; i2 < 8; ++i2)
#pragma unroll
        for (int j2 = 0; j2 < 8; ++j2)
          acc[i2][j2] = fmaf(a[i2], b[j2], acc[i2][j2]);
    }
    __syncthreads();
  }
#pragma unroll
  for (int i2 = 0; i2 < 8; ++i2) {
    int s = m0 + ((i2 < 4) ? (ty * 4 + i2) : (64 + ty * 4 + i2 - 4));
#pragma unroll
    for (int j2 = 0; j2 < 8; ++j2) {
      int o = n0 + ((j2 < 4) ? (tx * 4 + j2) : (64 + tx * 4 + j2 - 4));
      float v = acc[i2][j2];
      if (MODE == 0) {
        C[(size_t)s * HID + o] = v;
      } else {
        int h = o >> 7, d = o & 127;
        C[(((size_t)h * SEQ + s) << 7) + d] = v;
      }
    }
  }
}

// ---------------- RoPE tables (match jnp: fp32 t * fp32 inv_freq) ----------
__global__ void rope_tables_kernel(float* __restrict__ cosT, float* __restrict__ sinT) {
  int t = blockIdx.x;
  int i = threadIdx.x;  // 0..63
  double inv = pow(10000.0, -((double)(2 * i)) / 128.0);
  float ang = (float)t * (float)inv;
  cosT[t * 64 + i] = cosf(ang);
  sinT[t * 64 + i] = sinf(ang);
}

// ---------------- RoPE apply in-place on Q and K ---------------------------
__global__ void rope_apply_kernel(float* __restrict__ Q, float* __restrict__ K,
                                  const int* __restrict__ pos,
                                  const float* __restrict__ cosT,
                                  const float* __restrict__ sinT) {
  int d = threadIdx.x;           // 0..127
  int s = blockIdx.x;
  int h = blockIdx.y;
  float* X = blockIdx.z ? K : Q;
  float* row = X + (((size_t)h * SEQ + s) << 7);
  int p = pos[s];
  int i = d & 63;
  float c = cosT[p * 64 + i];
  float sn = sinT[p * 64 + i];
  float x  = row[d];
  float xo = row[(d < 64) ? (d + 64) : (d - 64)];
  float rot = (d < 64) ? -xo : xo;
  __syncthreads();               // all reads complete before any write
  row[d] = x * c + rot * sn;
}

// ---------------- Flash attention (fp32), per (head, 32-row q tile) --------
__global__ __launch_bounds__(256) void flash_kernel(const float* __restrict__ Q,
                                                    const float* __restrict__ K,
                                                    const float* __restrict__ V,
                                                    float* __restrict__ AO,
                                                    float* __restrict__ Mb,
                                                    float* __restrict__ Lb) {
  __shared__ float Qs[32][136];
  __shared__ float Ks[32][136];
  __shared__ float Vs[32][136];
  __shared__ float Ps[32][33];
  __shared__ float mrow[32], lrow[32], srow[32];
  const int tid = threadIdx.x;
  const int h = blockIdx.y, qt = blockIdx.x;
  const int q0 = qt * 32;
  const float* Qh = Q + (((size_t)h * SEQ + q0) << 7);
  const float* Kh = K + ((size_t)h * SEQ << 7);
  const float* Vh = V + ((size_t)h * SEQ << 7);
  for (int i = tid; i < 1024; i += 256) {
    int row = i >> 5, c4 = (i & 31) * 4;
    *(float4*)&Qs[row][c4] = *(const float4*)&Qh[i * 4];
  }
  if (tid < 32) { mrow[tid] = -INFINITY; lrow[tid] = 0.f; }
  const int r  = tid >> 3;   // q row 0..31
  const int sl = tid & 7;    // slot 0..7
  float o_acc[16] = {};
  for (int kt = 0; kt <= qt; ++kt) {
    __syncthreads();
    for (int i = tid; i < 1024; i += 256) {
      int row = i >> 5, c4 = (i & 31) * 4;
      *(float4*)&Ks[row][c4] = *(const float4*)&Kh[(size_t)kt * 4096 + i * 4];
      *(float4*)&Vs[row][c4] = *(const float4*)&Vh[(size_t)kt * 4096 + i * 4];
    }
    __syncthreads();
    // scores: this thread covers k = sl + 8j, j=0..3 for its row r
    float sacc[4] = {};
#pragma unroll 8
    for (int c = 0; c < 128; c += 4) {
      float4 qv = *(const float4*)&Qs[r][c];
#pragma unroll
      for (int j = 0; j < 4; ++j) {
        float4 kv = *(const float4*)&Ks[sl + 8 * j][c];
        sacc[j] = fmaf(qv.x, kv.x, sacc[j]);
        sacc[j] = fmaf(qv.y, kv.y, sacc[j]);
        sacc[j] = fmaf(qv.z, kv.z, sacc[j]);
        sacc[j] = fmaf(qv.w, kv.w, sacc[j]);
      }
    }
    const int qg = q0 + r;
#pragma unroll
    for (int j = 0; j < 4; ++j) {
      int kg = kt * 32 + sl + 8 * j;
      Ps[r][sl + 8 * j] = (kg <= qg) ? (sacc[j] * RSQRT_D) : -INFINITY;
    }
    __syncthreads();
    if (tid < 32) {
      int rr = tid;
      float mold = mrow[rr];
      float mt = mold;
#pragma unroll
      for (int k2 = 0; k2 < 32; ++k2) mt = fmaxf(mt, Ps[rr][k2]);
      float sc = expf(mold - mt);
      float ls = 0.f;
#pragma unroll
      for (int k2 = 0; k2 < 32; ++k2) {
        float p = expf(Ps[rr][k2] - mt);
        Ps[rr][k2] = p;
        ls += p;
      }
      mrow[rr] = mt;
      lrow[rr] = lrow[rr] * sc + ls;
      srow[rr] = sc;
    }
    __syncthreads();
    float sc = srow[r];
#pragma unroll
    for (int d2 = 0; d2 < 16; ++d2) o_acc[d2] *= sc;
#pragma unroll 4
    for (int k2 = 0; k2 < 32; ++k2) {
      float p = Ps[r][k2];
      float4 v0 = *(const float4*)&Vs[k2][sl * 4];
      float4 v1 = *(const float4*)&Vs[k2][sl * 4 + 32];
      float4 v2 = *(const float4*)&Vs[k2][sl * 4 + 64];
      float4 v3 = *(const float4*)&Vs[k2][sl * 4 + 96];
      o_acc[0]  = fmaf(p, v0.x, o_acc[0]);  o_acc[1]  = fmaf(p, v0.y, o_acc[1]);
      o_acc[2]  = fmaf(p, v0.z, o_acc[2]);  o_acc[3]  = fmaf(p, v0.w, o_acc[3]);
      o_acc[4]  = fmaf(p, v1.x, o_acc[4]);  o_acc[5]  = fmaf(p, v1.y, o_acc[5]);
      o_acc[6]  = fmaf(p, v1.z, o_acc[6]);  o_acc[7]  = fmaf(p, v1.w, o_acc[7]);
      o_acc[8]  = fmaf(p, v2.x, o_acc[8]);  o_acc[9]  = fmaf(p, v2.y, o_acc[9]);
      o_acc[10] = fmaf(p, v2.z, o_acc[10]); o_acc[11] = fmaf(p, v2.w, o_acc[11]);
      o_acc[12] = fmaf(p, v3.x, o_acc[12]); o_acc[13] = fmaf(p, v3.y, o_acc[13]);
      o_acc[14] = fmaf(p, v3.z, o_acc[14]); o_acc[15] = fmaf(p, v3.w, o_acc[15]);
    }
  }
  float linv = 1.f / lrow[r];
  int s = q0 + r;
  float* orow = &AO[(size_t)s * HID + h * 128];
#pragma unroll
  for (int m = 0; m < 4; ++m) {
    float4 w;
    w.x = o_acc[4 * m + 0] * linv; w.y = o_acc[4 * m + 1] * linv;
    w.z = o_acc[4 * m + 2] * linv; w.w = o_acc[4 * m + 3] * linv;
    *(float4*)&orow[sl * 4 + 32 * m] = w;
  }
  if (tid < 32) {
    Mb[h * SEQ + q0 + tid] = mrow[tid];
    Lb[h * SEQ + q0 + tid] = lrow[tid];
  }
}

// ---------------- Pass 2: hh_score[h,k] = sum_q exp(s-m_q)/l_q -------------
__global__ __launch_bounds__(256) void colsum_kernel(const float* __restrict__ Q,
                                                     const float* __restrict__ K,
                                                     const float* __restrict__ Mb,
                                                     const float* __restrict__ Lb,
                                                     float* __restrict__ HH) {
  __shared__ float Ks[32][136];
  __shared__ float Qs[32][136];
  __shared__ float ms[32], ls[32];
  __shared__ float part[32][9];
  const int tid = threadIdx.x;
  const int h = blockIdx.y, kt = blockIdx.x;
  const int k0 = kt * 32;
  const float* Kh = K + ((size_t)h * SEQ << 7);
  const float* Qh = Q + ((size_t)h * SEQ << 7);
  for (int i = tid; i < 1024; i += 256) {
    int row = i >> 5, c4 = (i & 31) * 4;
    *(float4*)&Ks[row][c4] = *(const float4*)&Kh[(size_t)k0 * 128 + i * 4];
  }
  const int c = tid >> 3;     // k column 0..31
  const int qsl = tid & 7;
  const int kg = k0 + c;
  float acc = 0.f;
  for (int qt = kt; qt < NKT; ++qt) {
    __syncthreads();
    for (int i = tid; i < 1024; i += 256) {
      int row = i >> 5, c4 = (i & 31) * 4;
      *(float4*)&Qs[row][c4] = *(const float4*)&Qh[(size_t)qt * 4096 + i * 4];
    }
    if (tid < 32) {
      ms[tid] = Mb[h * SEQ + qt * 32 + tid];
      ls[tid] = 1.f / Lb[h * SEQ + qt * 32 + tid];
    }
    __syncthreads();
    float dacc[4] = {};
#pragma unroll 8
    for (int cc = 0; cc < 128; cc += 4) {
      float4 kv = *(const float4*)&Ks[c][cc];
#pragma unroll
      for (int j = 0; j < 4; ++j) {
        float4 qv = *(const float4*)&Qs[qsl + 8 * j][cc];
        dacc[j] = fmaf(qv.x, kv.x, dacc[j]);
        dacc[j] = fmaf(qv.y, kv.y, dacc[j]);
        dacc[j] = fmaf(qv.z, kv.z, dacc[j]);
        dacc[j] = fmaf(qv.w, kv.w, dacc[j]);
      }
    }
#pragma unroll
    for (int j = 0; j < 4; ++j) {
      int qr = qsl + 8 * j;
      int qg = qt * 32 + qr;
      if (qg >= kg)
        acc += expf(dacc[j] * RSQRT_D - ms[qr]) * ls[qr];
    }
  }
  part[c][qsl] = acc;
  __syncthreads();
  if (qsl == 0) {
    float ssum = 0.f;
#pragma unroll
    for (int t2 = 0; t2 < 8; ++t2) ssum += part[c][t2];
    HH[h * SEQ + k0 + c] = ssum;
  }
}

// ---------------- Top-k (256 of first 1536) per head, jax tie-break --------
__global__ __launch_bounds__(256) void topk_kernel(const float* __restrict__ HH,
                                                   int* __restrict__ keep) {
  __shared__ float vals[SELN];
  __shared__ float rv[256];
  __shared__ int   ri[256];
  __shared__ int   sel[HHSZ];
  const int h = blockIdx.x, tid = threadIdx.x;
  for (int i = tid; i < SELN; i += 256) vals[i] = HH[h * SEQ + i];
  __syncthreads();
  for (int it = 0; it < HHSZ; ++it) {
    float bv = -INFINITY; int bi = 0x7fffffff;
    for (int i = tid; i < SELN; i += 256) {
      float v = vals[i];
      if (v > bv || (v == bv && i < bi)) { bv = v; bi = i; }
    }
    rv[tid] = bv; ri[tid] = bi;
    __syncthreads();
    for (int sft = 128; sft > 0; sft >>= 1) {
      if (tid < sft) {
        if (rv[tid + sft] > rv[tid] ||
            (rv[tid + sft] == rv[tid] && ri[tid + sft] < ri[tid])) {
          rv[tid] = rv[tid + sft]; ri[tid] = ri[tid + sft];
        }
      }
      __syncthreads();
    }
    if (tid == 0) { sel[it] = ri[0]; vals[ri[0]] = -INFINITY; }
    __syncthreads();
  }
  // odd-even transposition sort ascending (256 phases)
  for (int ph = 0; ph < HHSZ; ++ph) {
    int i = (ph & 1) + 2 * tid;
    if (i + 1 < HHSZ) {
      int a = sel[i], b = sel[i + 1];
      if (a > b) { sel[i] = b; sel[i + 1] = a; }
    }
    __syncthreads();
  }
  for (int i = tid; i < HHSZ; i += 256) keep[h * CACHE + i] = sel[i];
  for (int i = tid; i < RECENT; i += 256) keep[h * CACHE + HHSZ + i] = SELN + i;
}

// ---------------- Gather k_hh, v_hh, hh_score_kept -------------------------
__global__ void gather_kernel(const float* __restrict__ K, const float* __restrict__ V,
                              const float* __restrict__ HH, const int* __restrict__ keep,
                              float* __restrict__ k_out, float* __restrict__ v_out,
                              float* __restrict__ hh_out) {
  const int j = blockIdx.x;   // 0..767
  const int h = blockIdx.y;
  const int d = threadIdx.x;  // 0..127
  const int idx = keep[h * CACHE + j];
  size_t src = (((size_t)h * SEQ + idx) << 7) + d;
  size_t dst = (((size_t)h * CACHE + j) << 7) + d;
  k_out[dst] = K[src];
  v_out[dst] = V[src];
  if (d == 0) hh_out[h * CACHE + j] = HH[h * SEQ + idx];
}

extern "C" void kernel_launch(void* const* d_in, const int* in_sizes, int n_in,
                              void* d_out, int out_size, void* d_ws, size_t ws_size,
                              hipStream_t stream) {
  (void)in_sizes; (void)n_in; (void)out_size; (void)ws_size;
  const float* hs  = (const float*)d_in[0];
  const int*   pos = (const int*)d_in[1];
  const float* Wq  = (const float*)d_in[2];
  const float* Wk  = (const float*)d_in[3];
  const float* Wv  = (const float*)d_in[4];
  const float* Wo  = (const float*)d_in[5];

  float* out = (float*)d_out;                 // [2048][4096]
  float* khh = out + (size_t)SEQ * HID;       // [32][768][128]
  float* vhh = khh + (size_t)NH * CACHE * HD;
  float* hhk = vhh + (size_t)NH * CACHE * HD; // [32][768]

  float* W   = (float*)d_ws;
  float* Qw  = W;                              //  32 MB [h][s][d]
  float* Kw  = Qw + (size_t)NH * SEQ * HD;
  float* Vw  = Kw + (size_t)NH * SEQ * HD;
  float* AO  = Vw + (size_t)NH * SEQ * HD;     //  [s][4096]
  float* Mb  = AO + (size_t)SEQ * HID;
  float* Lb  = Mb + (size_t)NH * SEQ;
  float* HH  = Lb + (size_t)NH * SEQ;
  float* cosT = HH + (size_t)NH * SEQ;         // [2048][64]
  float* sinT = cosT + (size_t)SEQ * 64;
  int*   keep = (int*)(sinT + (size_t)SEQ * 64);

  gemm_nt<1><<<dim3(32, 16), 256, 0, stream>>>(hs, Wq, Qw);
  gemm_nt<1><<<dim3(32, 16), 256, 0, stream>>>(hs, Wk, Kw);
  gemm_nt<1><<<dim3(32, 16), 256, 0, stream>>>(hs, Wv, Vw);
  rope_tables_kernel<<<SEQ, 64, 0, stream>>>(cosT, sinT);
  rope_apply_kernel<<<dim3(SEQ, NH, 2), 128, 0, stream>>>(Qw, Kw, pos, cosT, sinT);
  flash_kernel<<<dim3(NKT, NH), 256, 0, stream>>>(Qw, Kw, Vw, AO, Mb, Lb);
  colsum_kernel<<<dim3(NKT, NH), 256, 0, stream>>>(Qw, Kw, Mb, Lb, HH);
  gemm_nt<0><<<dim3(32, 16), 256, 0, stream>>>(AO, Wo, out);
  topk_kernel<<<NH, 256, 0, stream>>>(HH, keep);
  gather_kernel<<<dim3(CACHE, NH), 128, 0, stream>>>(Kw, Vw, HH, keep, khh, vhh, hhk);
}

// Round 2
// 4728.266 us; speedup vs baseline: 1.4220x; 1.4220x over previous
//
#include <hip/hip_runtime.h>
#include <hip/hip_bf16.h>
#include <math.h>

#define HID 4096
#define NH 32
#define HD 128
#define SEQ 2048
#define NKT 64
#define HHSZ 256
#define RECENT 512
#define CACHE 768
#define SELN 1536
#define RSQRT_D 0.08838834764831845f

typedef unsigned short ushortT;
typedef __attribute__((ext_vector_type(8))) short short8;
typedef __attribute__((ext_vector_type(4))) float f32x4;

// ================= bf16 split helpers =====================================
__device__ __forceinline__ ushortT f2b(float f) {
  union { __hip_bfloat16 h; ushortT u; } v;
  v.h = __float2bfloat16(f);
  return v.u;
}
__device__ __forceinline__ float b2f(ushortT u) {
  union { unsigned int i; float f; } v;
  v.i = ((unsigned int)u) << 16;
  return v.f;
}
__device__ __forceinline__ void split3(float x, ushortT& h, ushortT& m, ushortT& l) {
  h = f2b(x);
  float r = x - b2f(h);
  m = f2b(r);
  float r2 = r - b2f(m);
  l = f2b(r2);
}
__device__ __forceinline__ void split2(float x, ushortT& h, ushortT& l) {
  h = f2b(x);
  l = f2b(x - b2f(h));
}

__global__ __launch_bounds__(256) void split3_kernel(const float* __restrict__ X,
    ushortT* __restrict__ o0, ushortT* __restrict__ o1, ushortT* __restrict__ o2, int n4) {
  int i = blockIdx.x * 256 + threadIdx.x;
  if (i >= n4) return;
  float4 x = ((const float4*)X)[i];
  ushort4 a, b, c;
  split3(x.x, a.x, b.x, c.x);
  split3(x.y, a.y, b.y, c.y);
  split3(x.z, a.z, b.z, c.z);
  split3(x.w, a.w, b.w, c.w);
  ((ushort4*)o0)[i] = a;
  ((ushort4*)o1)[i] = b;
  ((ushort4*)o2)[i] = c;
}
__global__ __launch_bounds__(256) void split2_kernel(const float* __restrict__ X,
    ushortT* __restrict__ o0, ushortT* __restrict__ o1, int n4) {
  int i = blockIdx.x * 256 + threadIdx.x;
  if (i >= n4) return;
  float4 x = ((const float4*)X)[i];
  ushort4 a, b;
  split2(x.x, a.x, b.x);
  split2(x.y, a.y, b.y);
  split2(x.z, a.z, b.z);
  split2(x.w, a.w, b.w);
  ((ushort4*)o0)[i] = a;
  ((ushort4*)o1)[i] = b;
}

// ================= async global->LDS ======================================
__device__ __forceinline__ void gload16(const void* g, void* lds) {
  __builtin_amdgcn_global_load_lds(
      (const __attribute__((address_space(1))) unsigned int*)g,
      (__attribute__((address_space(3))) unsigned int*)lds, 16, 0, 0);
}

// ================= split-bf16 MFMA GEMM  C = A * B^T ======================
// A[2048][4096], B[4096][4096] given as LEV bf16 level matrices each.
// LEV=3: products hh,hm,mh,mm,hl,lh (fp32-accurate). LEV=2: hh,hl,lh (~2^-16).
// MODE 0: C row-major [s][o].  MODE 1: scatter to [head][s][d].
// LDS tile layout: 8 subtiles of 16 rows; within subtile element (row, kc*8+j)
// at offset subtile*512 + kc*128 + row*8  (kc=0..3). This makes both the
// global_load_lds staging (wave-uniform base + lane*16) and the MFMA frag
// ds_read_b128 (2-way bank aliasing = free) work without padding.
template<int LEV, int MODE>
__global__ __launch_bounds__(256, 2) void gemm_mfma(
    const ushortT* __restrict__ A0, const ushortT* __restrict__ A1, const ushortT* __restrict__ A2,
    const ushortT* __restrict__ B0, const ushortT* __restrict__ B1, const ushortT* __restrict__ B2,
    float* __restrict__ C) {
  __shared__ ushortT As[LEV][4096];
  __shared__ ushortT Bs[LEV][4096];
  const int tid = threadIdx.x;
  const int w = tid >> 6, l = tid & 63;
  const int m16 = l & 15, quad = l >> 4;
  const int wr = w >> 1, wc = w & 1;
  const int m0 = blockIdx.y * 128, n0 = blockIdx.x * 128;
  const ushortT* Aarr[3] = {A0, A1, A2};
  const ushortT* Barr[3] = {B0, B1, B2};
  const size_t laneA = (size_t)(m0 + m16) * HID + quad * 8;
  const size_t laneB = (size_t)(n0 + m16) * HID + quad * 8;

  f32x4 acc[4][4] = {};

  for (int k0 = 0; k0 < HID; k0 += 32) {
    // ---- stage LEV*2 tiles of 128x32 bf16, 8 wave-insts each ----
#pragma unroll
    for (int u = 0; u < LEV * 4; ++u) {
      int t = u * 4 + w;          // 0 .. LEV*16-1
      int p = t >> 3, q = t & 7;  // tile p, 16-row chunk q
      const ushortT* g;
      ushortT* s;
      if (p < LEV) {
        g = Aarr[p] + laneA + (size_t)q * 16 * HID + k0;
        s = &As[p][q * 512];
      } else {
        g = Barr[p - LEV] + laneB + (size_t)q * 16 * HID + k0;
        s = &Bs[p - LEV][q * 512];
      }
      gload16(g, s);
    }
    __syncthreads();

    short8 af[LEV][4], bf[LEV][4];
#pragma unroll
    for (int v = 0; v < LEV; ++v)
#pragma unroll
      for (int i = 0; i < 4; ++i) {
        af[v][i] = *(const short8*)&As[v][(wr * 4 + i) * 512 + quad * 128 + m16 * 8];
        bf[v][i] = *(const short8*)&Bs[v][(wc * 4 + i) * 512 + quad * 128 + m16 * 8];
      }
#pragma unroll
    for (int i = 0; i < 4; ++i)
#pragma unroll
      for (int j = 0; j < 4; ++j) {
        acc[i][j] = __builtin_amdgcn_mfma_f32_16x16x32_bf16(af[0][i], bf[0][j], acc[i][j], 0, 0, 0);
        acc[i][j] = __builtin_amdgcn_mfma_f32_16x16x32_bf16(af[0][i], bf[1][j], acc[i][j], 0, 0, 0);
        acc[i][j] = __builtin_amdgcn_mfma_f32_16x16x32_bf16(af[1][i], bf[0][j], acc[i][j], 0, 0, 0);
        if (LEV == 3) {
          acc[i][j] = __builtin_amdgcn_mfma_f32_16x16x32_bf16(af[1][i], bf[1][j], acc[i][j], 0, 0, 0);
          acc[i][j] = __builtin_amdgcn_mfma_f32_16x16x32_bf16(af[0][i], bf[2][j], acc[i][j], 0, 0, 0);
          acc[i][j] = __builtin_amdgcn_mfma_f32_16x16x32_bf16(af[2][i], bf[0][j], acc[i][j], 0, 0, 0);
        }
      }
    __syncthreads();
  }

  const int row0 = m0 + wr * 64;
  const int col0 = n0 + wc * 64;
#pragma unroll
  for (int i = 0; i < 4; ++i)
#pragma unroll
    for (int j = 0; j < 4; ++j) {
#pragma unroll
      for (int r = 0; r < 4; ++r) {
        int row = row0 + i * 16 + quad * 4 + r;
        int col = col0 + j * 16 + m16;
        float v = acc[i][j][r];
        if (MODE == 0) {
          C[(size_t)row * HID + col] = v;
        } else {
          int h = col >> 7, d = col & 127;
          C[(((size_t)h * SEQ + row) << 7) + d] = v;
        }
      }
    }
}

// ================= fp32 fallback GEMM (round-0) ===========================
template<int MODE>
__global__ __launch_bounds__(256) void gemm_nt(const float* __restrict__ A,
                                               const float* __restrict__ B,
                                               float* __restrict__ C) {
  __shared__ float Asm[16][132];
  __shared__ float Bsm[16][132];
  const int tid = threadIdx.x;
  const int tx = tid & 15, ty = tid >> 4;
  const int m0 = blockIdx.y * 128, n0 = blockIdx.x * 128;
  float acc[8][8] = {};
  for (int k0 = 0; k0 < HID; k0 += 16) {
#pragma unroll
    for (int lp = 0; lp < 2; ++lp) {
      int i = tid + lp * 256;
      int row = i >> 2;
      int col = (i & 3) * 4;
      float4 av = *(const float4*)&A[(size_t)(m0 + row) * HID + k0 + col];
      Asm[col + 0][row] = av.x; Asm[col + 1][row] = av.y;
      Asm[col + 2][row] = av.z; Asm[col + 3][row] = av.w;
      float4 bv = *(const float4*)&B[(size_t)(n0 + row) * HID + k0 + col];
      Bsm[col + 0][row] = bv.x; Bsm[col + 1][row] = bv.y;
      Bsm[col + 2][row] = bv.z; Bsm[col + 3][row] = bv.w;
    }
    __syncthreads();
#pragma unroll
    for (int kk = 0; kk < 16; ++kk) {
      float a[8], b[8];
      *(float4*)&a[0] = *(const float4*)&Asm[kk][ty * 4];
      *(float4*)&a[4] = *(const float4*)&Asm[kk][64 + ty * 4];
      *(float4*)&b[0] = *(const float4*)&Bsm[kk][tx * 4];
      *(float4*)&b[4] = *(const float4*)&Bsm[kk][64 + tx * 4];
#pragma unroll
      for (int i2 = 0; i2 < 8; ++i2)
#pragma unroll
        for (int j2 = 0; j2 < 8; ++j2)
          acc[i2][j2] = fmaf(a[i2], b[j2], acc[i2][j2]);
    }
    __syncthreads();
  }
#pragma unroll
  for (int i2 = 0; i2 < 8; ++i2) {
    int s = m0 + ((i2 < 4) ? (ty * 4 + i2) : (64 + ty * 4 + i2 - 4));
#pragma unroll
    for (int j2 = 0; j2 < 8; ++j2) {
      int o = n0 + ((j2 < 4) ? (tx * 4 + j2) : (64 + tx * 4 + j2 - 4));
      float v = acc[i2][j2];
      if (MODE == 0) {
        C[(size_t)s * HID + o] = v;
      } else {
        int h = o >> 7, d = o & 127;
        C[(((size_t)h * SEQ + s) << 7) + d] = v;
      }
    }
  }
}

// ================= RoPE ====================================================
__global__ void rope_tables_kernel(float* __restrict__ cosT, float* __restrict__ sinT) {
  int t = blockIdx.x;
  int i = threadIdx.x;  // 0..63
  double inv = pow(10000.0, -((double)(2 * i)) / 128.0);
  float ang = (float)t * (float)inv;
  cosT[t * 64 + i] = cosf(ang);
  sinT[t * 64 + i] = sinf(ang);
}

__global__ void rope_apply_kernel(float* __restrict__ Q, float* __restrict__ K,
                                  const int* __restrict__ pos,
                                  const float* __restrict__ cosT,
                                  const float* __restrict__ sinT) {
  int d = threadIdx.x;           // 0..127
  int s = blockIdx.x;
  int h = blockIdx.y;
  float* X = blockIdx.z ? K : Q;
  float* row = X + (((size_t)h * SEQ + s) << 7);
  int p = pos[s];
  int i = d & 63;
  float c = cosT[p * 64 + i];
  float sn = sinT[p * 64 + i];
  float x  = row[d];
  float xo = row[(d < 64) ? (d + 64) : (d - 64)];
  float rot = (d < 64) ? -xo : xo;
  __syncthreads();
  row[d] = x * c + rot * sn;
}

// ================= Flash attention (fp32) =================================
__global__ __launch_bounds__(256) void flash_kernel(const float* __restrict__ Q,
                                                    const float* __restrict__ K,
                                                    const float* __restrict__ V,
                                                    float* __restrict__ AO,
                                                    float* __restrict__ Mb,
                                                    float* __restrict__ Lb) {
  __shared__ float Qs[32][136];
  __shared__ float Ks[32][136];
  __shared__ float Vs[32][136];
  __shared__ float Ps[32][33];
  __shared__ float mrow[32], lrow[32], srow[32];
  const int tid = threadIdx.x;
  const int h = blockIdx.y, qt = blockIdx.x;
  const int q0 = qt * 32;
  const float* Qh = Q + (((size_t)h * SEQ + q0) << 7);
  const float* Kh = K + ((size_t)h * SEQ << 7);
  const float* Vh = V + ((size_t)h * SEQ << 7);
  for (int i = tid; i < 1024; i += 256) {
    int row = i >> 5, c4 = (i & 31) * 4;
    *(float4*)&Qs[row][c4] = *(const float4*)&Qh[i * 4];
  }
  if (tid < 32) { mrow[tid] = -INFINITY; lrow[tid] = 0.f; }
  const int r  = tid >> 3;
  const int sl = tid & 7;
  float o_acc[16] = {};
  for (int kt = 0; kt <= qt; ++kt) {
    __syncthreads();
    for (int i = tid; i < 1024; i += 256) {
      int row = i >> 5, c4 = (i & 31) * 4;
      *(float4*)&Ks[row][c4] = *(const float4*)&Kh[(size_t)kt * 4096 + i * 4];
      *(float4*)&Vs[row][c4] = *(const float4*)&Vh[(size_t)kt * 4096 + i * 4];
    }
    __syncthreads();
    float sacc[4] = {};
#pragma unroll 8
    for (int c = 0; c < 128; c += 4) {
      float4 qv = *(const float4*)&Qs[r][c];
#pragma unroll
      for (int j = 0; j < 4; ++j) {
        float4 kv = *(const float4*)&Ks[sl + 8 * j][c];
        sacc[j] = fmaf(qv.x, kv.x, sacc[j]);
        sacc[j] = fmaf(qv.y, kv.y, sacc[j]);
        sacc[j] = fmaf(qv.z, kv.z, sacc[j]);
        sacc[j] = fmaf(qv.w, kv.w, sacc[j]);
      }
    }
    const int qg = q0 + r;
#pragma unroll
    for (int j = 0; j < 4; ++j) {
      int kg = kt * 32 + sl + 8 * j;
      Ps[r][sl + 8 * j] = (kg <= qg) ? (sacc[j] * RSQRT_D) : -INFINITY;
    }
    __syncthreads();
    if (tid < 32) {
      int rr = tid;
      float mold = mrow[rr];
      float mt = mold;
#pragma unroll
      for (int k2 = 0; k2 < 32; ++k2) mt = fmaxf(mt, Ps[rr][k2]);
      float sc = expf(mold - mt);
      float ls = 0.f;
#pragma unroll
      for (int k2 = 0; k2 < 32; ++k2) {
        float p = expf(Ps[rr][k2] - mt);
        Ps[rr][k2] = p;
        ls += p;
      }
      mrow[rr] = mt;
      lrow[rr] = lrow[rr] * sc + ls;
      srow[rr] = sc;
    }
    __syncthreads();
    float sc = srow[r];
#pragma unroll
    for (int d2 = 0; d2 < 16; ++d2) o_acc[d2] *= sc;
#pragma unroll 4
    for (int k2 = 0; k2 < 32; ++k2) {
      float p = Ps[r][k2];
      float4 v0 = *(const float4*)&Vs[k2][sl * 4];
      float4 v1 = *(const float4*)&Vs[k2][sl * 4 + 32];
      float4 v2 = *(const float4*)&Vs[k2][sl * 4 + 64];
      float4 v3 = *(const float4*)&Vs[k2][sl * 4 + 96];
      o_acc[0]  = fmaf(p, v0.x, o_acc[0]);  o_acc[1]  = fmaf(p, v0.y, o_acc[1]);
      o_acc[2]  = fmaf(p, v0.z, o_acc[2]);  o_acc[3]  = fmaf(p, v0.w, o_acc[3]);
      o_acc[4]  = fmaf(p, v1.x, o_acc[4]);  o_acc[5]  = fmaf(p, v1.y, o_acc[5]);
      o_acc[6]  = fmaf(p, v1.z, o_acc[6]);  o_acc[7]  = fmaf(p, v1.w, o_acc[7]);
      o_acc[8]  = fmaf(p, v2.x, o_acc[8]);  o_acc[9]  = fmaf(p, v2.y, o_acc[9]);
      o_acc[10] = fmaf(p, v2.z, o_acc[10]); o_acc[11] = fmaf(p, v2.w, o_acc[11]);
      o_acc[12] = fmaf(p, v3.x, o_acc[12]); o_acc[13] = fmaf(p, v3.y, o_acc[13]);
      o_acc[14] = fmaf(p, v3.z, o_acc[14]); o_acc[15] = fmaf(p, v3.w, o_acc[15]);
    }
  }
  float linv = 1.f / lrow[r];
  int s = q0 + r;
  float* orow = &AO[(size_t)s * HID + h * 128];
#pragma unroll
  for (int m = 0; m < 4; ++m) {
    float4 wv;
    wv.x = o_acc[4 * m + 0] * linv; wv.y = o_acc[4 * m + 1] * linv;
    wv.z = o_acc[4 * m + 2] * linv; wv.w = o_acc[4 * m + 3] * linv;
    *(float4*)&orow[sl * 4 + 32 * m] = wv;
  }
  if (tid < 32) {
    Mb[h * SEQ + q0 + tid] = mrow[tid];
    Lb[h * SEQ + q0 + tid] = lrow[tid];
  }
}

// ================= colsum pass ============================================
__global__ __launch_bounds__(256) void colsum_kernel(const float* __restrict__ Q,
                                                     const float* __restrict__ K,
                                                     const float* __restrict__ Mb,
                                                     const float* __restrict__ Lb,
                                                     float* __restrict__ HH) {
  __shared__ float Ks[32][136];
  __shared__ float Qs[32][136];
  __shared__ float ms[32], ls[32];
  __shared__ float part[32][9];
  const int tid = threadIdx.x;
  const int h = blockIdx.y, kt = blockIdx.x;
  const int k0 = kt * 32;
  const float* Kh = K + ((size_t)h * SEQ << 7);
  const float* Qh = Q + ((size_t)h * SEQ << 7);
  for (int i = tid; i < 1024; i += 256) {
    int row = i >> 5, c4 = (i & 31) * 4;
    *(float4*)&Ks[row][c4] = *(const float4*)&Kh[(size_t)k0 * 128 + i * 4];
  }
  const int c = tid >> 3;
  const int qsl = tid & 7;
  const int kg = k0 + c;
  float acc = 0.f;
  for (int qt = kt; qt < NKT; ++qt) {
    __syncthreads();
    for (int i = tid; i < 1024; i += 256) {
      int row = i >> 5, c4 = (i & 31) * 4;
      *(float4*)&Qs[row][c4] = *(const float4*)&Qh[(size_t)qt * 4096 + i * 4];
    }
    if (tid < 32) {
      ms[tid] = Mb[h * SEQ + qt * 32 + tid];
      ls[tid] = 1.f / Lb[h * SEQ + qt * 32 + tid];
    }
    __syncthreads();
    float dacc[4] = {};
#pragma unroll 8
    for (int cc = 0; cc < 128; cc += 4) {
      float4 kv = *(const float4*)&Ks[c][cc];
#pragma unroll
      for (int j = 0; j < 4; ++j) {
        float4 qv = *(const float4*)&Qs[qsl + 8 * j][cc];
        dacc[j] = fmaf(qv.x, kv.x, dacc[j]);
        dacc[j] = fmaf(qv.y, kv.y, dacc[j]);
        dacc[j] = fmaf(qv.z, kv.z, dacc[j]);
        dacc[j] = fmaf(qv.w, kv.w, dacc[j]);
      }
    }
#pragma unroll
    for (int j = 0; j < 4; ++j) {
      int qr = qsl + 8 * j;
      int qg = qt * 32 + qr;
      if (qg >= kg)
        acc += expf(dacc[j] * RSQRT_D - ms[qr]) * ls[qr];
    }
  }
  part[c][qsl] = acc;
  __syncthreads();
  if (qsl == 0) {
    float ssum = 0.f;
#pragma unroll
    for (int t2 = 0; t2 < 8; ++t2) ssum += part[c][t2];
    HH[h * SEQ + k0 + c] = ssum;
  }
}

// ================= top-k ===================================================
__global__ __launch_bounds__(256) void topk_kernel(const float* __restrict__ HH,
                                                   int* __restrict__ keep) {
  __shared__ float vals[SELN];
  __shared__ float rv[256];
  __shared__ int   ri[256];
  __shared__ int   sel[HHSZ];
  const int h = blockIdx.x, tid = threadIdx.x;
  for (int i = tid; i < SELN; i += 256) vals[i] = HH[h * SEQ + i];
  __syncthreads();
  for (int it = 0; it < HHSZ; ++it) {
    float bv = -INFINITY; int bi = 0x7fffffff;
    for (int i = tid; i < SELN; i += 256) {
      float v = vals[i];
      if (v > bv || (v == bv && i < bi)) { bv = v; bi = i; }
    }
    rv[tid] = bv; ri[tid] = bi;
    __syncthreads();
    for (int sft = 128; sft > 0; sft >>= 1) {
      if (tid < sft) {
        if (rv[tid + sft] > rv[tid] ||
            (rv[tid + sft] == rv[tid] && ri[tid + sft] < ri[tid])) {
          rv[tid] = rv[tid + sft]; ri[tid] = ri[tid + sft];
        }
      }
      __syncthreads();
    }
    if (tid == 0) { sel[it] = ri[0]; vals[ri[0]] = -INFINITY; }
    __syncthreads();
  }
  for (int ph = 0; ph < HHSZ; ++ph) {
    int i = (ph & 1) + 2 * tid;
    if (i + 1 < HHSZ) {
      int a = sel[i], b = sel[i + 1];
      if (a > b) { sel[i] = b; sel[i + 1] = a; }
    }
    __syncthreads();
  }
  for (int i = tid; i < HHSZ; i += 256) keep[h * CACHE + i] = sel[i];
  for (int i = tid; i < RECENT; i += 256) keep[h * CACHE + HHSZ + i] = SELN + i;
}

// ================= gather ==================================================
__global__ void gather_kernel(const float* __restrict__ K, const float* __restrict__ V,
                              const float* __restrict__ HH, const int* __restrict__ keep,
                              float* __restrict__ k_out, float* __restrict__ v_out,
                              float* __restrict__ hh_out) {
  const int j = blockIdx.x;
  const int h = blockIdx.y;
  const int d = threadIdx.x;
  const int idx = keep[h * CACHE + j];
  size_t src = (((size_t)h * SEQ + idx) << 7) + d;
  size_t dst = (((size_t)h * CACHE + j) << 7) + d;
  k_out[dst] = K[src];
  v_out[dst] = V[src];
  if (d == 0) hh_out[h * CACHE + j] = HH[h * SEQ + idx];
}

// ================= launch ==================================================
extern "C" void kernel_launch(void* const* d_in, const int* in_sizes, int n_in,
                              void* d_out, int out_size, void* d_ws, size_t ws_size,
                              hipStream_t stream) {
  (void)in_sizes; (void)n_in; (void)out_size;
  const float* hs  = (const float*)d_in[0];
  const int*   pos = (const int*)d_in[1];
  const float* Wq  = (const float*)d_in[2];
  const float* Wk  = (const float*)d_in[3];
  const float* Wv  = (const float*)d_in[4];
  const float* Wo  = (const float*)d_in[5];

  float* out = (float*)d_out;                 // [2048][4096]
  float* khh = out + (size_t)SEQ * HID;       // [32][768][128]
  float* vhh = khh + (size_t)NH * CACHE * HD;
  float* hhk = vhh + (size_t)NH * CACHE * HD; // [32][768]

  char* p = (char*)d_ws;
  auto alloc = [&](size_t bytes) { char* r = p; p += (bytes + 255) & ~(size_t)255; return r; };

  float* Qw   = (float*)alloc((size_t)NH * SEQ * HD * 4);
  float* Kw   = (float*)alloc((size_t)NH * SEQ * HD * 4);
  float* Vw   = (float*)alloc((size_t)NH * SEQ * HD * 4);
  float* AO   = (float*)alloc((size_t)SEQ * HID * 4);
  float* Mb   = (float*)alloc((size_t)NH * SEQ * 4);
  float* Lb   = (float*)alloc((size_t)NH * SEQ * 4);
  float* HH   = (float*)alloc((size_t)NH * SEQ * 4);
  float* cosT = (float*)alloc((size_t)SEQ * 64 * 4);
  float* sinT = (float*)alloc((size_t)SEQ * 64 * 4);
  int*   keep = (int*)alloc((size_t)NH * CACHE * 4);
  // bf16 split buffers
  ushortT* hsH = (ushortT*)alloc((size_t)SEQ * HID * 2);
  ushortT* hsM = (ushortT*)alloc((size_t)SEQ * HID * 2);
  ushortT* hsL = (ushortT*)alloc((size_t)SEQ * HID * 2);
  ushortT* WH  = (ushortT*)alloc((size_t)HID * HID * 2);
  ushortT* WM  = (ushortT*)alloc((size_t)HID * HID * 2);
  ushortT* WL  = (ushortT*)alloc((size_t)HID * HID * 2);
  const size_t needed = (size_t)(p - (char*)d_ws);
  const bool use_mfma = ws_size >= needed;

  const dim3 ggrid(32, 16);
  const int n4hs = SEQ * HID / 4;    // 2097152
  const int n4w  = HID * HID / 4;    // 4194304

  if (use_mfma) {
    split3_kernel<<<n4hs / 256, 256, 0, stream>>>(hs, hsH, hsM, hsL, n4hs);
    split3_kernel<<<n4w / 256, 256, 0, stream>>>(Wq, WH, WM, WL, n4w);
    gemm_mfma<3, 1><<<ggrid, 256, 0, stream>>>(hsH, hsM, hsL, WH, WM, WL, Qw);
    split3_kernel<<<n4w / 256, 256, 0, stream>>>(Wk, WH, WM, WL, n4w);
    gemm_mfma<3, 1><<<ggrid, 256, 0, stream>>>(hsH, hsM, hsL, WH, WM, WL, Kw);
    split2_kernel<<<n4w / 256, 256, 0, stream>>>(Wv, WH, WM, n4w);
    gemm_mfma<2, 1><<<ggrid, 256, 0, stream>>>(hsH, hsM, nullptr, WH, WM, nullptr, Vw);
  } else {
    gemm_nt<1><<<ggrid, 256, 0, stream>>>(hs, Wq, Qw);
    gemm_nt<1><<<ggrid, 256, 0, stream>>>(hs, Wk, Kw);
    gemm_nt<1><<<ggrid, 256, 0, stream>>>(hs, Wv, Vw);
  }

  rope_tables_kernel<<<SEQ, 64, 0, stream>>>(cosT, sinT);
  rope_apply_kernel<<<dim3(SEQ, NH, 2), 128, 0, stream>>>(Qw, Kw, pos, cosT, sinT);
  flash_kernel<<<dim3(NKT, NH), 256, 0, stream>>>(Qw, Kw, Vw, AO, Mb, Lb);
  colsum_kernel<<<dim3(NKT, NH), 256, 0, stream>>>(Qw, Kw, Mb, Lb, HH);

  if (use_mfma) {
    split2_kernel<<<n4w / 256, 256, 0, stream>>>(Wo, WH, WM, n4w);
    split2_kernel<<<n4hs / 256, 256, 0, stream>>>(AO, hsH, hsM, n4hs);  // reuse hs buffers
    gemm_mfma<2, 0><<<ggrid, 256, 0, stream>>>(hsH, hsM, nullptr, WH, WM, nullptr, out);
  } else {
    gemm_nt<0><<<ggrid, 256, 0, stream>>>(AO, Wo, out);
  }

  topk_kernel<<<NH, 256, 0, stream>>>(HH, keep);
  gather_kernel<<<dim3(CACHE, NH), 128, 0, stream>>>(Kw, Vw, HH, keep, khh, vhh, hhk);
}